// Round 5
// baseline (472.383 us; speedup 1.0000x reference)
//
#include <hip/hip_runtime.h>
#include <hip/hip_bf16.h>

// x[16384,4096] fp32, v[4096,256] fp32 -> out[16384,1] fp32
// out = 0.5*(sum_f (x@v)_f^2 - sum_n x_n^2 * w_n), w_n = sum_f v_nf^2
#define B_DIM 16384
#define K_DIM 4096
#define F_DIM 256
#define BM 32
#define BK 64
#define NSTEP (K_DIM / BK)   // 64

typedef short bf16x8 __attribute__((ext_vector_type(8)));
typedef float f32x4 __attribute__((ext_vector_type(4)));

static __device__ __forceinline__ ushort f2bf(float f) {
    union { __hip_bfloat16 h; ushort s; } u;
    u.h = __float2bfloat16(f);
    return u.s;
}

static __device__ __forceinline__ void gload_lds16(const void* g, void* l) {
    __builtin_amdgcn_global_load_lds(
        (const __attribute__((address_space(1))) unsigned int*)g,
        (__attribute__((address_space(3))) unsigned int*)l, 16, 0, 0);
}

// ---- prep: w[n] = sum_f v[n][f]^2 (fp32). 8 waves/block, one row per wave.
__global__ __launch_bounds__(512) void prep_w(const float* __restrict__ v,
                                              float* __restrict__ w) {
    const int lane = threadIdx.x & 63;
    const int n = blockIdx.x * 8 + (threadIdx.x >> 6);
    const float4 vv = *reinterpret_cast<const float4*>(v + (size_t)n * F_DIM + lane * 4);
    float s = vv.x * vv.x + vv.y * vv.y + vv.z * vv.z + vv.w * vv.w;
#pragma unroll
    for (int m = 1; m < 64; m <<= 1) s += __shfl_xor(s, m);
    if (lane == 0) w[n] = s;
}

// ---- prep: vT[f][k] bf16 = v[k][f], coalesced via LDS transpose.
__global__ __launch_bounds__(512) void prep_t(const float* __restrict__ v,
                                              ushort* __restrict__ vT) {
    __shared__ ushort T[256][72];
    const int tid = threadIdx.x;
    const int n0 = blockIdx.x * 64;
    const int wid = tid >> 6;
    const int f0 = (tid & 63) * 4;
#pragma unroll
    for (int j = 0; j < 8; ++j) {
        const int r = j * 8 + wid;
        const float4 vv = *reinterpret_cast<const float4*>(v + (size_t)(n0 + r) * F_DIM + f0);
        T[f0 + 0][r] = f2bf(vv.x);
        T[f0 + 1][r] = f2bf(vv.y);
        T[f0 + 2][r] = f2bf(vv.z);
        T[f0 + 3][r] = f2bf(vv.w);
    }
    __syncthreads();
    const int nb = (tid & 7) * 8;
#pragma unroll
    for (int s = 0; s < 4; ++s) {
        const int f = s * 64 + (tid >> 3);
        const uint4 val = *reinterpret_cast<const uint4*>(&T[f][nb]);
        *reinterpret_cast<uint4*>(vT + (size_t)f * K_DIM + n0 + nb) = val;
    }
}

// ---- main fused kernel.
// grid 512 (BM=32 rows/block), block 256 thr = 4 waves; wave wc owns cols wc*64.
// A: fp32 LDS double-buffer (2x8KB), XOR-swizzled, staged via global_load_lds
//    from inverse-swizzled global source. Consumers cvt fp32->bf16 from LDS.
// B: registers, double-buffered, loaded straight from L2-resident vT.
// S2: wave 0 accumulates x^2*w in fp32 from its A-fragment reads.
__global__ __launch_bounds__(256, 3) void fm_kernel(const float* __restrict__ x,
                                                    const ushort* __restrict__ vT,
                                                    const float* __restrict__ w,
                                                    float* __restrict__ out) {
    __shared__ float Ab[2][BM * BK];   // fp32, 8 KB each, rows 256 B, swizzled
    __shared__ float red[BM][4];
    __shared__ float s2red[BM];

    const int tid = threadIdx.x;
    const int lane = tid & 63;
    const int wc = tid >> 6;          // wave id = col group (0..3)
    const int l15 = lane & 15;
    const int koff = lane >> 4;       // 0..3

    const int mbase = blockIdx.x * BM;

    // -------- A staging (all 256 threads) --------
    // call 1: LDS bytes [tid*16, +16) -> row tid>>4 (0..15)
    // call 2: +4096               -> row 16 + tid>>4
    const int srow = tid >> 4;
    const int sj = (tid & 15) * 16;                 // dest byte col in 256-B row
    const int sjj = sj ^ ((srow & 7) << 4);         // inverse-swizzled src byte
    const float* gx1 = x + (size_t)(mbase + srow) * K_DIM + (sjj >> 2);
    const float* gx2 = x + (size_t)(mbase + 16 + srow) * K_DIM + (sjj >> 2);

    auto stageA = [&](int k0, int buf) {
        char* base = reinterpret_cast<char*>(&Ab[buf][0]) + wc * 1024;  // wave-uniform
        gload_lds16(gx1 + k0, base);
        gload_lds16(gx2 + k0, base + 4096);
    };

    // -------- A fragment read constants --------
    int aRo[2], aXm[2];
#pragma unroll
    for (int m = 0; m < 2; ++m) {
        const int r = m * 16 + l15;
        aRo[m] = r * 256;
        aXm[m] = (r & 7) << 4;
    }
    const int cbase = koff * 32;      // fp32 byte offset of 8-elem k-slice

    // -------- B load base: vT[col][k], col = wc*64 + n*16 + l15 --------
    const ushort* vb = vT + (size_t)(wc * 64 + l15) * K_DIM + koff * 8;
    const float* wb = w + koff * 8;   // for S2 (wave 0)

    f32x4 acc[2][4] = {};
    float s2m0 = 0.f, s2m1 = 0.f;
    bf16x8 bA[4][2], bB[4][2];

    auto loadB = [&](int k0, bf16x8 (&bn)[4][2]) {
#pragma unroll
        for (int n = 0; n < 4; ++n)
#pragma unroll
            for (int ks = 0; ks < 2; ++ks)
                bn[n][ks] = *reinterpret_cast<const bf16x8*>(
                    vb + (size_t)n * 16 * K_DIM + k0 + ks * 32);
    };

    auto compute = [&](int k0, int buf, bf16x8 (&bc)[4][2]) {
        const char* Ac = reinterpret_cast<const char*>(&Ab[buf][0]);
        bf16x8 af[2][2];
#pragma unroll
        for (int ks = 0; ks < 2; ++ks) {
            float4 wlo = {0, 0, 0, 0}, whi = {0, 0, 0, 0};
            if (wc == 0) {
                wlo = *reinterpret_cast<const float4*>(wb + k0 + ks * 32);
                whi = *reinterpret_cast<const float4*>(wb + k0 + ks * 32 + 4);
            }
#pragma unroll
            for (int m = 0; m < 2; ++m) {
                const int c0 = (ks * 128 + cbase) ^ aXm[m];
                const int c1 = (ks * 128 + cbase + 16) ^ aXm[m];
                const f32x4 lo = *reinterpret_cast<const f32x4*>(Ac + aRo[m] + c0);
                const f32x4 hi = *reinterpret_cast<const f32x4*>(Ac + aRo[m] + c1);
                bf16x8 a;
                a[0] = (short)f2bf(lo[0]); a[1] = (short)f2bf(lo[1]);
                a[2] = (short)f2bf(lo[2]); a[3] = (short)f2bf(lo[3]);
                a[4] = (short)f2bf(hi[0]); a[5] = (short)f2bf(hi[1]);
                a[6] = (short)f2bf(hi[2]); a[7] = (short)f2bf(hi[3]);
                af[m][ks] = a;
                if (wc == 0) {
                    const float t = lo[0] * lo[0] * wlo.x + lo[1] * lo[1] * wlo.y
                                  + lo[2] * lo[2] * wlo.z + lo[3] * lo[3] * wlo.w
                                  + hi[0] * hi[0] * whi.x + hi[1] * hi[1] * whi.y
                                  + hi[2] * hi[2] * whi.z + hi[3] * hi[3] * whi.w;
                    if (m == 0) s2m0 += t; else s2m1 += t;
                }
            }
        }
#pragma unroll
        for (int ks = 0; ks < 2; ++ks)
#pragma unroll
            for (int m = 0; m < 2; ++m)
#pragma unroll
                for (int n = 0; n < 4; ++n)
                    acc[m][n] = __builtin_amdgcn_mfma_f32_16x16x32_bf16(
                        af[m][ks], bc[n][ks], acc[m][n], 0, 0, 0);
    };

    // -------- prologue --------
    stageA(0, 0);
    loadB(0, bA);
    __syncthreads();

    // -------- main loop, unrolled x2 for static reg double-buffer --------
    for (int t = 0; t < NSTEP; t += 2) {
        // even step: compute(buf0, bA), prefetch t+1 -> (buf1, bB)
        stageA((t + 1) * BK, 1);
        loadB((t + 1) * BK, bB);
        compute(t * BK, 0, bA);
        __syncthreads();
        // odd step: compute(buf1, bB), prefetch t+2 -> (buf0, bA)
        if (t + 2 < NSTEP) {
            stageA((t + 2) * BK, 0);
            loadB((t + 2) * BK, bA);
        }
        compute((t + 1) * BK, 1, bB);
        __syncthreads();
    }

    // -------- epilogue --------
    // C/D layout: col = l15 (+n*16 +wc*64), row = koff*4 + j (+m*16)
#pragma unroll
    for (int m = 0; m < 2; ++m) {
#pragma unroll
        for (int j = 0; j < 4; ++j) {
            float s = 0.f;
#pragma unroll
            for (int n = 0; n < 4; ++n) { const float y = acc[m][n][j]; s += y * y; }
            s += __shfl_xor(s, 1);
            s += __shfl_xor(s, 2);
            s += __shfl_xor(s, 4);
            s += __shfl_xor(s, 8);
            if (l15 == 0) red[m * 16 + koff * 4 + j][wc] = s;
        }
    }
    if (wc == 0) {
        s2m0 += __shfl_xor(s2m0, 16); s2m0 += __shfl_xor(s2m0, 32);
        s2m1 += __shfl_xor(s2m1, 16); s2m1 += __shfl_xor(s2m1, 32);
        if (lane < 16) { s2red[lane] = s2m0; s2red[16 + lane] = s2m1; }
    }
    __syncthreads();
    if (tid < BM) {
        out[mbase + tid] = 0.5f * (red[tid][0] + red[tid][1] + red[tid][2]
                                   + red[tid][3] - s2red[tid]);
    }
}

extern "C" void kernel_launch(void* const* d_in, const int* in_sizes, int n_in,
                              void* d_out, int out_size, void* d_ws, size_t ws_size,
                              hipStream_t stream) {
    const float* x = (const float*)d_in[0];
    const float* v = (const float*)d_in[1];
    float* out = (float*)d_out;

    // ws: [0, 2MB) vT bf16[256][4096]; then w fp32[4096]
    ushort* vT = (ushort*)d_ws;
    float* w = (float*)((char*)d_ws + (size_t)F_DIM * K_DIM * sizeof(ushort));

    prep_w<<<K_DIM / 8, 512, 0, stream>>>(v, w);
    prep_t<<<K_DIM / 64, 512, 0, stream>>>(v, vT);
    fm_kernel<<<B_DIM / BM, 256, 0, stream>>>(x, vT, w, out);
}

// Round 6
// 424.477 us; speedup vs baseline: 1.1129x; 1.1129x over previous
//
#include <hip/hip_runtime.h>
#include <hip/hip_bf16.h>

// x[16384,4096] fp32, v[4096,256] fp32 -> out[16384,1] fp32
// out = 0.5*(sum_f (x@v)_f^2 - sum_n x_n^2 * w_n), w_n = sum_f v_nf^2
#define B_DIM 16384
#define K_DIM 4096
#define F_DIM 256
#define BM 32
#define BK 64
#define NSTEP (K_DIM / BK)   // 64

typedef short bf16x8 __attribute__((ext_vector_type(8)));
typedef float f32x4 __attribute__((ext_vector_type(4)));

static __device__ __forceinline__ ushort f2bf(float f) {
    union { __hip_bfloat16 h; ushort s; } u;
    u.h = __float2bfloat16(f);
    return u.s;
}

// ---- prep: w[n] = sum_f v[n][f]^2 (fp32). 8 waves/block, one row per wave.
__global__ __launch_bounds__(512) void prep_w(const float* __restrict__ v,
                                              float* __restrict__ w) {
    const int lane = threadIdx.x & 63;
    const int n = blockIdx.x * 8 + (threadIdx.x >> 6);
    const float4 vv = *reinterpret_cast<const float4*>(v + (size_t)n * F_DIM + lane * 4);
    float s = vv.x * vv.x + vv.y * vv.y + vv.z * vv.z + vv.w * vv.w;
#pragma unroll
    for (int m = 1; m < 64; m <<= 1) s += __shfl_xor(s, m);
    if (lane == 0) w[n] = s;
}

// ---- prep: vT[f][k] bf16 = v[k][f], coalesced via LDS transpose.
__global__ __launch_bounds__(512) void prep_t(const float* __restrict__ v,
                                              ushort* __restrict__ vT) {
    __shared__ ushort T[256][72];
    const int tid = threadIdx.x;
    const int n0 = blockIdx.x * 64;
    const int wid = tid >> 6;
    const int f0 = (tid & 63) * 4;
#pragma unroll
    for (int j = 0; j < 8; ++j) {
        const int r = j * 8 + wid;
        const float4 vv = *reinterpret_cast<const float4*>(v + (size_t)(n0 + r) * F_DIM + f0);
        T[f0 + 0][r] = f2bf(vv.x);
        T[f0 + 1][r] = f2bf(vv.y);
        T[f0 + 2][r] = f2bf(vv.z);
        T[f0 + 3][r] = f2bf(vv.w);
    }
    __syncthreads();
    const int nb = (tid & 7) * 8;
#pragma unroll
    for (int s = 0; s < 4; ++s) {
        const int f = s * 64 + (tid >> 3);
        const uint4 val = *reinterpret_cast<const uint4*>(&T[f][nb]);
        *reinterpret_cast<uint4*>(vT + (size_t)f * K_DIM + n0 + nb) = val;
    }
}

struct APend { float4 xa, xb, wa, wb; };
struct BReg { bf16x8 v[4][2]; };

// ---- main fused kernel.
// grid 512 (BM=32), 256 thr = 4 waves; wave wc owns cols wc*64..+64.
// Counted-wait 2-phase pipeline, raw s_barrier (no vmcnt(0) drain in loop):
//   phase t: issue A(t+2)->regs, B(t+1)->regs | compute tile t (LDS A + reg B)
//            | cvt+S2+swizzled ds_write of A(t+1) | lgkmcnt(0); s_barrier.
__global__ __launch_bounds__(256, 2) void fm_kernel(const float* __restrict__ x,
                                                    const ushort* __restrict__ vT,
                                                    const float* __restrict__ w,
                                                    float* __restrict__ out) {
    __shared__ ushort As[2][BM * BK];   // bf16, 4 KB each, 128-B rows, XOR-swizzled
    __shared__ float red[BM][4];
    __shared__ float s2red[BM];

    const int tid = threadIdx.x;
    const int lane = tid & 63;
    const int wc = tid >> 6;          // wave id = col group (0..3)
    const int l15 = lane & 15;
    const int koff = lane >> 4;       // 0..3
    const int mbase = blockIdx.x * BM;

    // -------- staging geometry: thread owns row srow, k-chunk kb..kb+8 --------
    const int srow = tid >> 3;            // 0..31
    const int kb = (tid & 7) * 8;         // 0..56
    const float* px = x + (size_t)(mbase + srow) * K_DIM + kb;
    const float* pw = w + kb;
    const int wbyte = srow * 128 + (((tid & 7) * 16) ^ ((srow & 7) << 4));

    // -------- fragment read offsets (XOR matches write side) --------
    int aoff[2][2];
#pragma unroll
    for (int m = 0; m < 2; ++m)
#pragma unroll
        for (int ks = 0; ks < 2; ++ks)
            aoff[m][ks] = (m * 16 + l15) * 128
                        + ((koff * 16 + ks * 64) ^ ((l15 & 7) << 4));
    const ushort* vb = vT + (size_t)(wc * 64 + l15) * K_DIM + koff * 8;

    float s2 = 0.f;
    f32x4 acc[2][4] = {};
    APend p0, p1;
    BReg b0, b1;

    auto loadA = [&](int t, APend& p) {
        const int k0 = (t < NSTEP ? t : NSTEP - 1) * BK;
        p.xa = *reinterpret_cast<const float4*>(px + k0);
        p.xb = *reinterpret_cast<const float4*>(px + k0 + 4);
        p.wa = *reinterpret_cast<const float4*>(pw + k0);
        p.wb = *reinterpret_cast<const float4*>(pw + k0 + 4);
    };
    auto loadB = [&](int t, BReg& b) {
        const int k0 = (t < NSTEP ? t : NSTEP - 1) * BK;
#pragma unroll
        for (int n = 0; n < 4; ++n)
#pragma unroll
            for (int ks = 0; ks < 2; ++ks)
                b.v[n][ks] = *reinterpret_cast<const bf16x8*>(
                    vb + (size_t)n * 16 * K_DIM + k0 + ks * 32);
    };
    auto writeA = [&](ushort* dst, const APend& p) {
        s2 += p.xa.x * p.xa.x * p.wa.x + p.xa.y * p.xa.y * p.wa.y
            + p.xa.z * p.xa.z * p.wa.z + p.xa.w * p.xa.w * p.wa.w
            + p.xb.x * p.xb.x * p.wb.x + p.xb.y * p.xb.y * p.wb.y
            + p.xb.z * p.xb.z * p.wb.z + p.xb.w * p.xb.w * p.wb.w;
        uint4 pk;
        pk.x = (uint)f2bf(p.xa.x) | ((uint)f2bf(p.xa.y) << 16);
        pk.y = (uint)f2bf(p.xa.z) | ((uint)f2bf(p.xa.w) << 16);
        pk.z = (uint)f2bf(p.xb.x) | ((uint)f2bf(p.xb.y) << 16);
        pk.w = (uint)f2bf(p.xb.z) | ((uint)f2bf(p.xb.w) << 16);
        *reinterpret_cast<uint4*>(reinterpret_cast<char*>(dst) + wbyte) = pk;
    };
    auto compute = [&](const ushort* Asrc, const BReg& b) {
        const char* Ac = reinterpret_cast<const char*>(Asrc);
        bf16x8 af[2][2];
#pragma unroll
        for (int m = 0; m < 2; ++m)
#pragma unroll
            for (int ks = 0; ks < 2; ++ks)
                af[m][ks] = *reinterpret_cast<const bf16x8*>(Ac + aoff[m][ks]);
#pragma unroll
        for (int ks = 0; ks < 2; ++ks)
#pragma unroll
            for (int m = 0; m < 2; ++m)
#pragma unroll
                for (int n = 0; n < 4; ++n)
                    acc[m][n] = __builtin_amdgcn_mfma_f32_16x16x32_bf16(
                        af[m][ks], b.v[n][ks], acc[m][n], 0, 0, 0);
    };

    // -------- prologue: tile0 A in LDS, tile0 B in regs, tile1 A pending --------
    loadA(0, p0);
    loadA(1, p1);
    loadB(0, b0);
    writeA(As[0], p0);
    asm volatile("s_waitcnt lgkmcnt(0)" ::: "memory");
    __builtin_amdgcn_s_barrier();

    // -------- main loop: 2 tiles per iteration, no vmcnt(0) drains --------
    for (int t = 0; t < NSTEP; t += 2) {
        // even phase: tile t from As[0]/b0
        loadA(t + 2, p0);
        loadB(t + 1, b1);
        asm volatile("" ::: "memory");
        compute(As[0], b0);
        if (t + 1 < NSTEP) writeA(As[1], p1);   // p1 loaded 1+ phase ago
        asm volatile("s_waitcnt lgkmcnt(0)" ::: "memory");
        __builtin_amdgcn_s_barrier();

        // odd phase: tile t+1 from As[1]/b1
        loadA(t + 3, p1);
        loadB(t + 2, b0);
        asm volatile("" ::: "memory");
        compute(As[1], b1);
        if (t + 2 < NSTEP) writeA(As[0], p0);   // p0 loaded 1+ phase ago
        asm volatile("s_waitcnt lgkmcnt(0)" ::: "memory");
        __builtin_amdgcn_s_barrier();
    }

    // -------- epilogue --------
    // C/D layout: col = l15 (+n*16 +wc*64), row = koff*4 + j (+m*16)
#pragma unroll
    for (int m = 0; m < 2; ++m) {
#pragma unroll
        for (int j = 0; j < 4; ++j) {
            float s = 0.f;
#pragma unroll
            for (int n = 0; n < 4; ++n) { const float y = acc[m][n][j]; s += y * y; }
            s += __shfl_xor(s, 1);
            s += __shfl_xor(s, 2);
            s += __shfl_xor(s, 4);
            s += __shfl_xor(s, 8);
            if (l15 == 0) red[m * 16 + koff * 4 + j][wc] = s;
        }
    }
    // s2: thread holds partial for row srow; reduce over the 8 threads per row.
    s2 += __shfl_xor(s2, 1);
    s2 += __shfl_xor(s2, 2);
    s2 += __shfl_xor(s2, 4);
    if ((tid & 7) == 0) s2red[srow] = s2;
    __syncthreads();
    if (tid < BM) {
        out[mbase + tid] = 0.5f * (red[tid][0] + red[tid][1] + red[tid][2]
                                   + red[tid][3] - s2red[tid]);
    }
}

extern "C" void kernel_launch(void* const* d_in, const int* in_sizes, int n_in,
                              void* d_out, int out_size, void* d_ws, size_t ws_size,
                              hipStream_t stream) {
    const float* x = (const float*)d_in[0];
    const float* v = (const float*)d_in[1];
    float* out = (float*)d_out;

    // ws: [0, 2MB) vT bf16[256][4096]; then w fp32[4096]
    ushort* vT = (ushort*)d_ws;
    float* w = (float*)((char*)d_ws + (size_t)F_DIM * K_DIM * sizeof(ushort));

    prep_w<<<K_DIM / 8, 512, 0, stream>>>(v, w);
    prep_t<<<K_DIM / 64, 512, 0, stream>>>(v, vT);
    fm_kernel<<<B_DIM / BM, 256, 0, stream>>>(x, vT, w, out);
}